// Round 14
// baseline (219.947 us; speedup 1.0000x reference)
//
#include <hip/hip_runtime.h>
#include <stdint.h>

typedef __bf16 bf16_t;
typedef __bf16 bf16x8 __attribute__((ext_vector_type(8)));
typedef float f32x4 __attribute__((ext_vector_type(4)));

// async global->LDS, 16B per lane; HW dest = wave-uniform base + lane*16
__device__ __forceinline__ void gload_lds16(const void* g, void* l) {
  __builtin_amdgcn_global_load_lds(
      (const __attribute__((address_space(1))) uint32_t*)g,
      (__attribute__((address_space(3))) uint32_t*)l, 16, 0, 0);
}

// ---------------- fused cast f32 -> bf16 for 3 buffers ----------------
__global__ void cast3_f32_bf16(const float* __restrict__ a, bf16_t* __restrict__ ao, int n4a,
                               const float* __restrict__ b, bf16_t* __restrict__ bo, int n4b,
                               const float* __restrict__ c, bf16_t* __restrict__ co, int n4c) {
  int i = blockIdx.x * blockDim.x + threadIdx.x;
  int stride = gridDim.x * blockDim.x;
  int total = n4a + n4b + n4c;
  for (int idx = i; idx < total; idx += stride) {
    const float* src; bf16_t* dst; int j = idx;
    if (j < n4a) { src = a; dst = ao; }
    else if ((j -= n4a) < n4b) { src = b; dst = bo; }
    else { j -= n4b; src = c; dst = co; }
    float4 v = reinterpret_cast<const float4*>(src)[j];
    union { bf16_t b[4]; uint2 u; } pk;
    pk.b[0] = (bf16_t)v.x; pk.b[1] = (bf16_t)v.y;
    pk.b[2] = (bf16_t)v.z; pk.b[3] = (bf16_t)v.w;
    reinterpret_cast<uint2*>(dst)[j] = pk.u;
  }
}

// ---- occupancy-first GEMM: C[M][N] = A[M][K]*B[N][K]^T (+bias) ----
// BM=256 BN=128 BK=32, K=1024 (NT=32). 512 thr = 8 waves (4M x 2N), wave
// tile 64x64 = 4x4 frags 16x16x32 bf16 -> acc only 64 VGPR. Total regs
// ~120 <= 128 cap (__launch_bounds__(512,4)) -> 4 waves/SIMD = TWO
// independent blocks/CU (the r4-r13 plateau: acc 128 + frags pushed regs
// to ~236 -> 1 block/CU, 2 waves/SIMD, full lockstep, MfmaUtil pinned 35%).
// Two unsynchronized blocks de-phase -> one block's MFMA overlaps the
// other's LDS/stage/barrier. No setprio (m190: negative on GEMM).
// 3-slot LDS ring (72KB/block, 2 blocks = 144 <= 160), staged 2 ahead,
// 3 gloads/stage; steady vmcnt(3) (stage t+1 landed, t+2's 3 in flight),
// vmcnt(0) only last 2 tiles; ONE barrier/tile.
// Swizzle: LDS[r][c16] = G[r][c16 ^ ((r>>1)&3)] both sides (r4: 0 conflicts).
// Grid: XCD x owns bx slab [x*8,x*8+8); by-fast (A panel 0.5MB L2-hot).
template <bool BF16_OUT>
__global__ __launch_bounds__(512, 4)
void gemm_oc(const bf16_t* __restrict__ A, const bf16_t* __restrict__ B,
             void* __restrict__ Cout, const float* __restrict__ bias,
             int N, int nby) {
  constexpr int K = 1024, NT = 32;
  __shared__ bf16_t Al[3][256 * 32];  // 3 x 16KB
  __shared__ bf16_t Bl[3][128 * 32];  // 3 x 8KB

  const int tid = threadIdx.x;
  const int l = tid & 63, w = tid >> 6;
  const int wm = w >> 1, wn = w & 1;  // 4M x 2N

  const int bid = blockIdx.x;
  const int xcd = bid & 7, idx = bid >> 3;
  const int bxsub = idx / nby, by = idx - bxsub * nby;  // by-fast
  const int bx = xcd * 8 + bxsub;  // nbx = 64 (M = 16384)
  const int m0 = bx * 256, n0 = by * 128;

  // staging (8KB/issue = 128 rows): thread t: row = t>>2, lds chunk t&3,
  // global chunk = (t&3) ^ ((row>>1)&3) = (t&3)^((t>>3)&3)  (inverse swz)
  const int ra = tid >> 2;
  const int ca = ((tid & 3) ^ ((tid >> 3) & 3)) * 8;
  const bf16_t* pA0 = A + (size_t)(m0 + ra) * K + ca;
  const bf16_t* pA1 = A + (size_t)(m0 + 128 + ra) * K + ca;
  const bf16_t* pB0 = B + (size_t)(n0 + ra) * K + ca;

#define STAGE(t_, s_) do { const int kt_ = (t_) * 32;  \
    gload_lds16(pA0 + kt_, &Al[s_][tid * 8]);          \
    gload_lds16(pA1 + kt_, &Al[s_][4096 + tid * 8]);   \
    gload_lds16(pB0 + kt_, &Bl[s_][tid * 8]); } while (0)

  // frag reads: row = base + (l&15) + 16i (bases mult of 64) -> (row>>1)&3
  // = (l>>1)&3 ; swizzled chunk = (l>>4) ^ ((l>>1)&3)
  const int abase = (wm * 64 + (l & 15)) * 32;
  const int bbase = (wn * 64 + (l & 15)) * 32;
  const int ck = ((l >> 4) ^ ((l >> 1) & 3)) * 8;

  f32x4 acc[4][4] = {};
  bf16x8 af[4], bfr[4];

  STAGE(0, 0); STAGE(1, 1);
  asm volatile("s_waitcnt vmcnt(3)" ::: "memory");  // tile 0 landed
  __builtin_amdgcn_s_barrier();

  int slot = 0;
  for (int t = 0; t < NT; ++t) {
    int s2 = slot + 2; if (s2 >= 3) s2 -= 3;
    if (t + 2 < NT) STAGE(t + 2, s2);  // slot(t-1): reads drained last tile
    const bf16_t* As = Al[slot];
    const bf16_t* Bs = Bl[slot];
#pragma unroll
    for (int i = 0; i < 4; ++i)
      af[i] = *reinterpret_cast<const bf16x8*>(&As[abase + i * 512 + ck]);
#pragma unroll
    for (int j = 0; j < 4; ++j)
      bfr[j] = *reinterpret_cast<const bf16x8*>(&Bs[bbase + j * 512 + ck]);
#pragma unroll
    for (int i = 0; i < 4; ++i)
#pragma unroll
      for (int j = 0; j < 4; ++j)
        acc[i][j] = __builtin_amdgcn_mfma_f32_16x16x32_bf16(af[i], bfr[j],
                                                            acc[i][j], 0, 0, 0);
    // counted gate: stage(t+1) landed (t+2's 3 may fly); drain only at end
    if (t + 2 < NT) asm volatile("s_waitcnt vmcnt(3)" ::: "memory");
    else            asm volatile("s_waitcnt vmcnt(0)" ::: "memory");
    asm volatile("" ::: "memory");
    __builtin_amdgcn_s_barrier();
    asm volatile("" ::: "memory");
    slot = (slot + 1 == 3) ? 0 : slot + 1;
  }
#undef STAGE

  // ---- epilogue: C/D layout col = lane&15, row = (lane>>4)*4 + reg ----
  const int r0 = m0 + wm * 64 + (l >> 4) * 4;
  const int c0 = n0 + wn * 64 + (l & 15);
  if (BF16_OUT) {
    bf16_t* C = (bf16_t*)Cout;
#pragma unroll
    for (int i = 0; i < 4; ++i)
#pragma unroll
      for (int j = 0; j < 4; ++j)
#pragma unroll
        for (int r = 0; r < 4; ++r)
          C[(size_t)(r0 + i * 16 + r) * N + (c0 + j * 16)] = (bf16_t)acc[i][j][r];
  } else {
    float* C = (float*)Cout;
#pragma unroll
    for (int i = 0; i < 4; ++i)
#pragma unroll
      for (int j = 0; j < 4; ++j)
#pragma unroll
        for (int r = 0; r < 4; ++r)
          C[(size_t)(r0 + i * 16 + r) * N + (c0 + j * 16)] =
              acc[i][j][r] + bias[c0 + j * 16];
  }
}

// ---------------- per-token head-attention ----------------
__global__ __launch_bounds__(256)
void attn_heads(const bf16_t* __restrict__ qkv, bf16_t* __restrict__ out) {
  __shared__ float s[4][3072];
  const int w = threadIdx.x >> 6, l = threadIdx.x & 63;
  const size_t t = (size_t)blockIdx.x * 4 + w;
  const bf16_t* src = qkv + t * 3072;
#pragma unroll
  for (int i = 0; i < 6; ++i) {
    int f = (i * 64 + l) * 8;
    bf16x8 v = *reinterpret_cast<const bf16x8*>(&src[f]);
#pragma unroll
    for (int jj = 0; jj < 8; ++jj) s[w][f + jj] = (float)v[jj];
  }
  __syncthreads();

  const int h = l >> 2, ss = l & 3;
  float qr[16];
  const float* qb = &s[w][h * 192 + ss * 16];
#pragma unroll
  for (int d = 0; d < 16; ++d) qr[d] = qb[d];

  float sc[16];
#pragma unroll
  for (int g = 0; g < 16; ++g) {
    const float* kk = &s[w][g * 192 + 64 + ss * 16];
    float p = 0.f;
#pragma unroll
    for (int d = 0; d < 16; ++d) p += qr[d] * kk[d];
    p += __shfl_xor(p, 1);
    p += __shfl_xor(p, 2);
    sc[g] = p * 0.125f;
  }
  float m = sc[0];
#pragma unroll
  for (int g = 1; g < 16; ++g) m = fmaxf(m, sc[g]);
  float sum = 0.f;
#pragma unroll
  for (int g = 0; g < 16; ++g) { sc[g] = __expf(sc[g] - m); sum += sc[g]; }
  float inv = 1.f / sum;

  float o[16] = {};
#pragma unroll
  for (int g = 0; g < 16; ++g) {
    float a = sc[g] * inv;
    const float* vv = &s[w][g * 192 + 128 + ss * 16];
#pragma unroll
    for (int d = 0; d < 16; ++d) o[d] += a * vv[d];
  }
  union { bf16_t b[16]; uint4 u[2]; } pk;
#pragma unroll
  for (int d = 0; d < 16; ++d) pk.b[d] = (bf16_t)o[d];
  uint4* dst = reinterpret_cast<uint4*>(out + t * 1024 + h * 64 + ss * 16);
  dst[0] = pk.u[0];
  dst[1] = pk.u[1];
}

// ---------------- launch ----------------
extern "C" void kernel_launch(void* const* d_in, const int* in_sizes, int n_in,
                              void* d_out, int out_size, void* d_ws, size_t ws_size,
                              hipStream_t stream) {
  const float* x     = (const float*)d_in[0];  // [8,2048,1024]
  const float* Wqkv  = (const float*)d_in[1];  // [3072,1024]
  const float* Wproj = (const float*)d_in[2];  // [1024,1024]
  const float* bproj = (const float*)d_in[3];  // [1024]
  float* out = (float*)d_out;

  const int M = 8 * 2048;   // 16384 tokens -> 64 bx blocks of 256
  const int DM = 1024;
  const int F = 3072;

  char* ws = (char*)d_ws;
  bf16_t* xb     = (bf16_t*)ws;  ws += (size_t)M * DM * 2;
  bf16_t* wqkvb  = (bf16_t*)ws;  ws += (size_t)F * DM * 2;
  bf16_t* wprojb = (bf16_t*)ws;  ws += (size_t)DM * DM * 2;
  bf16_t* qkvb   = (bf16_t*)ws;  ws += (size_t)M * F * 2;
  bf16_t* attnb  = (bf16_t*)ws;

  cast3_f32_bf16<<<2048, 256, 0, stream>>>(x, xb, M * DM / 4,
                                           Wqkv, wqkvb, F * DM / 4,
                                           Wproj, wprojb, DM * DM / 4);

  // GEMM1: [16384,1024] x [3072,1024]^T -> bf16 [16384,3072]
  gemm_oc<true><<<(M / 256) * (F / 128), 512, 0, stream>>>(
      xb, wqkvb, (void*)qkvb, nullptr, F, F / 128);

  attn_heads<<<M / 4, 256, 0, stream>>>(qkvb, attnb);

  // GEMM2: [16384,1024] x [1024,1024]^T -> f32 [16384,1024] + bias
  gemm_oc<false><<<(M / 256) * (DM / 128), 512, 0, stream>>>(
      attnb, wprojb, (void*)out, bproj, DM, DM / 128);
}